// Round 9
// baseline (156.439 us; speedup 1.0000x reference)
//
#include <hip/hip_runtime.h>
#include <math.h>

// B=64, F=4096, HOP=64, SR=16000.  out = sin(f32ops(cumsum(repeat(freq,64)) - f0))
//
// FROZEN NUMERICS (validated R4, absmax 1.953e-2 < 2e-2):
//  - cumsum = XLA/TPU ReduceWindowRewriter blocked scan, base_length=16
//    (HS16 in blocks; block sums scanned 262144->16384->1024->64->4; length-4
//    sequential base; exclusive broadcast-add back down).
//  - post-ops bit-exact f32:  ph = inner0 + excl1;  d = ph - f0;
//    t = d * f32(2pi);  u = t / 16000.0f (IEEE div);  x = u + pm;  libm sinf(x).
//
// R5: fused 2pi/16000 + __sinf(large arg) -> 2.246e-2 fail (~3e-3 over). Banned.
// R6/R7/R8 post-mortem: all three DROPPED the "- f0" subtraction (transcription
// bug propagated from R6) -> absmax 0.407 = max(freq[b,0])*2pi/16000. The
// sin-implementation experiments were invalid. R4's chain incl. libm sinf is
// the validated config; R9 = R8's perf structure with "- f0" restored.

#define BB   64
#define FF   4096
#define NPER (FF * 64)       // 2^18 per row

// In-place Hillis-Steele inclusive scan of 16 f32 values (shifts 1,2,4,8).
__device__ inline void hs16(float* x) {
#pragma unroll
    for (int s = 1; s < 16; s <<= 1) {
#pragma unroll
        for (int c = 15; c >= 0; --c) {
            if (c >= s) x[c] = x[c] + x[c - s];
        }
    }
}

// ---------------------------------------------------------------------------
// Kernel 1: per-row blocked-scan upper levels; writes scan1 (16384 f32/row) =
// inclusive scan of v1[j] = 16*fr[j/4] with the rewriter's bracketing.
// ---------------------------------------------------------------------------
__global__ __launch_bounds__(256)
void prescan_kernel(const float* __restrict__ freq, float* __restrict__ scan1g) {
    __shared__ float fr[4096];     // 16 KB
    __shared__ float v2[1024];     // level-1 block sums
    __shared__ float v3[64];       // level-2 block sums
    __shared__ float inner3s[64];
    __shared__ float v4s[4];
    __shared__ float s4s[4];
    __shared__ float scan3[64];
    __shared__ float scan2[1024];

    const int b = blockIdx.x, tid = threadIdx.x;
    const float* row = freq + b * FF;
    for (int i = tid; i < FF; i += 256) fr[i] = row[i];
    __syncthreads();

    // level 1: v1-block J = frames 4J..4J+3, 4 copies each of 16*fr (exact)
    for (int J = tid; J < 1024; J += 256) {
        float x[16];
#pragma unroll
        for (int c = 0; c < 16; ++c) x[c] = 16.0f * fr[4 * J + (c >> 2)];
        hs16(x);
        v2[J] = x[15];
    }
    __syncthreads();

    // level 2
    for (int K = tid; K < 64; K += 256) {
        float x[16];
#pragma unroll
        for (int c = 0; c < 16; ++c) x[c] = v2[16 * K + c];
        hs16(x);
        v3[K] = x[15];
    }
    __syncthreads();

    // level 3: 4 independent HS16s in parallel (value-identical to serial)
    if (tid < 4) {
        const int M = tid;
        float x[16];
#pragma unroll
        for (int c = 0; c < 16; ++c) x[c] = v3[16 * M + c];
        hs16(x);
#pragma unroll
        for (int c = 0; c < 16; ++c) inner3s[16 * M + c] = x[c];
        v4s[M] = x[15];
    }
    __syncthreads();

    // length-4 base: sequential left fold
    if (tid == 0) {
        s4s[0] = v4s[0];
        s4s[1] = s4s[0] + v4s[1];
        s4s[2] = s4s[1] + v4s[2];
        s4s[3] = s4s[2] + v4s[3];
    }
    __syncthreads();

    // scan3[K] = inner3[K] + excl4
    for (int K = tid; K < 64; K += 256) {
        const int M = K >> 4;
        const float e4 = (M == 0) ? 0.0f : s4s[M - 1];
        scan3[K] = inner3s[K] + e4;
    }
    __syncthreads();

    // scan2[J] = inner2[J] + excl3
    for (int K = tid; K < 64; K += 256) {
        float x[16];
#pragma unroll
        for (int c = 0; c < 16; ++c) x[c] = v2[16 * K + c];
        hs16(x);
        const float e3 = (K == 0) ? 0.0f : scan3[K - 1];
        for (int c = 0; c < 16; ++c) scan2[16 * K + c] = x[c] + e3;
    }
    __syncthreads();

    // scan1[j] = inner1[j] + excl2  -> global
    float* srow = scan1g + b * 16384;
    for (int J = tid; J < 1024; J += 256) {
        float x[16];
#pragma unroll
        for (int c = 0; c < 16; ++c) x[c] = 16.0f * fr[4 * J + (c >> 2)];
        hs16(x);
        const float e2 = (J == 0) ? 0.0f : scan2[J - 1];
        for (int c = 0; c < 16; ++c) srow[16 * J + c] = x[c] + e2;
    }
}

// ---------------------------------------------------------------------------
// Kernel 2: one thread per 16-block (16 outputs). Per-element ops bit-identical
// to R4:
//   ph = inn[c] + excl1;  d = ph - f0;  t = d*2pi_f32;  u = t/16000.0f;
//   x = u + pm;  sinf(x)      [the "- f0" is phase - phase[...,0] — REQUIRED]
// inn[0..7] = HS16-on-constant table {fr,2fr,2fr+fr,4fr,...,8fr};
// inn[8..15] = 8fr + inn[0..7]; inn[15] = 8fr+8fr (all same adds as R4).
// ---------------------------------------------------------------------------
__global__ __launch_bounds__(256)
void osc_kernel(const float* __restrict__ freq,
                const float* __restrict__ pm,
                const float* __restrict__ scan1g,
                float* __restrict__ out) {
    const int ib   = blockIdx.x * blockDim.x + threadIdx.x;  // 16-block id
    const int b    = ib >> 14;            // 16384 16-blocks per row
    const int jrow = ib & 16383;          // 16-block index within row
    const int f    = jrow >> 2;           // 4 16-blocks per frame

    const float fr = freq[b * FF + f];
    const float f0 = freq[b * FF];
    const float excl1 = (jrow == 0) ? 0.0f : scan1g[b * 16384 + jrow - 1];

    // HS16-on-constant table (same rounded adds as R4)
    const float t1 = fr;
    const float t2 = fr + fr;          // exact
    const float t3 = t2 + t1;
    const float t4 = t2 + t2;          // exact
    const float t5 = t4 + t1;
    const float t6 = t4 + t2;
    const float t7 = t4 + t3;
    const float t8 = t4 + t4;          // exact
    const float inn[16] = {t1, t2, t3, t4, t5, t6, t7, t8,
                           t8 + t1, t8 + t2, t8 + t3, t8 + t4,
                           t8 + t5, t8 + t6, t8 + t7, t8 + t8};

    const float4* pmv  = (const float4*)pm + (size_t)ib * 4;
    float4*       outv = (float4*)out + (size_t)ib * 4;
    const float TWOPI_F = 6.28318530717958647692f;   // rounds to f32(2*pi)

#pragma unroll
    for (int g = 0; g < 4; ++g) {
        const float4 p4 = pmv[g];
        const float pj[4] = {p4.x, p4.y, p4.z, p4.w};
        float oj[4];
#pragma unroll
        for (int k = 0; k < 4; ++k) {
            const int c = 4 * g + k;           // compile-time after unroll
            const float ph = inn[c] + excl1;   // rewriter's broadcast add
            const float d  = ph - f0;          // phase - phase[...,0]  (R6-R8 bug: was missing)
            const float t  = d * TWOPI_F;      // f32 mul
            const float u  = t / 16000.0f;     // IEEE f32 div (do NOT fuse)
            const float x  = u + pj[k];        // f32 add
            oj[k] = sinf(x);                   // libm sinf — validated in R4
        }
        float4 o;
        o.x = oj[0]; o.y = oj[1]; o.z = oj[2]; o.w = oj[3];
        outv[g] = o;
    }
}

// ---------------------------------------------------------------------------
extern "C" void kernel_launch(void* const* d_in, const int* in_sizes, int n_in,
                              void* d_out, int out_size, void* d_ws, size_t ws_size,
                              hipStream_t stream) {
    const float* freq = (const float*)d_in[0];   // [B, F] f32
    const float* pm   = (const float*)d_in[1];   // [B, F*64] f32
    float* outp   = (float*)d_out;               // [B, F*64] f32
    float* scan1g = (float*)d_ws;                // 64 * 16384 f32 = 4 MB

    prescan_kernel<<<dim3(BB), dim3(256), 0, stream>>>(freq, scan1g);

    const int nthreads = (BB * NPER) / 16;       // 1,048,576 threads
    osc_kernel<<<dim3(nthreads / 256), dim3(256), 0, stream>>>(freq, pm, scan1g, outp);
}